// Round 1
// baseline (411.158 us; speedup 1.0000x reference)
//
#include <hip/hip_runtime.h>
#include <hip/hip_bf16.h>

// RolePositionBiasedAttention: B=16384, N=10, D=256, H=8, DH=32
// Pipeline per chunk:  prep_wt (once) -> gemm_qkv (bf16 MFMA) -> attn (VALU fp32) -> gemm_wo (bf16 MFMA, fp32 out)

typedef __attribute__((ext_vector_type(8))) short bf16x8;
typedef __attribute__((ext_vector_type(4))) float f32x4;

__device__ __forceinline__ unsigned short f2bf(float f) {
  union { __hip_bfloat16 h; unsigned short u; } cv;
  cv.h = __float2bfloat16(f);
  return cv.u;
}
__device__ __forceinline__ float bflo(unsigned int u) { return __uint_as_float(u << 16); }
__device__ __forceinline__ float bfhi(unsigned int u) { return __uint_as_float(u & 0xffff0000u); }

// ---------------- prep: WT[w][n][k] = bf16(W[k][n]), w in {Q,K,V,O} ----------------
__global__ void prep_wt_kernel(const float* __restrict__ WQ, const float* __restrict__ WK,
                               const float* __restrict__ WV, const float* __restrict__ WO,
                               __hip_bfloat16* __restrict__ wt) {
  const int k = blockIdx.x;      // 0..255
  const int n = threadIdx.x;     // 0..255 (coalesced read of W row k)
  wt[0 * 65536 + n * 256 + k] = __float2bfloat16(WQ[k * 256 + n]);
  wt[1 * 65536 + n * 256 + k] = __float2bfloat16(WK[k * 256 + n]);
  wt[2 * 65536 + n * 256 + k] = __float2bfloat16(WV[k * 256 + n]);
  wt[3 * 65536 + n * 256 + k] = __float2bfloat16(WO[k * 256 + n]);
}

// ---------------- GEMM body: C[M][256] = A[M][256] @ W, W given as WT[n][k] bf16 ----------------
// BM=BN=128, BK=64, 256 threads (4 waves, 2x2), 16x16x32 bf16 MFMA, acc 4x4 frags/wave.
// LDS tiles [128][64] bf16, XOR swizzle: 16B-chunk c stored at (c ^ (row&7)).
template<bool A_F32, bool OUT_F32>
__device__ __forceinline__ void gemm_body(const void* __restrict__ Ap,
                                          const __hip_bfloat16* __restrict__ BT,
                                          void* __restrict__ Cp)
{
  __shared__ __align__(16) char lds[32768];
  char* As = lds;
  char* Bs = lds + 16384;
  const int m0 = blockIdx.x * 128;
  const int n0 = blockIdx.y * 128;
  const int t = threadIdx.x;
  const int lane = t & 63;
  const int wave = t >> 6;
  const int wm = wave >> 1, wn = wave & 1;
  const int g = lane >> 4, cx = lane & 15;
  const int r = t >> 1;        // staging row 0..127
  const int half = t & 1;      // staging k-half

  f32x4 acc[4][4];
  #pragma unroll
  for (int a = 0; a < 4; ++a)
    #pragma unroll
    for (int b = 0; b < 4; ++b) acc[a][b] = (f32x4){0.f, 0.f, 0.f, 0.f};

  #pragma unroll 1
  for (int ks = 0; ks < 4; ++ks) {
    const int k0 = ks * 64;
    if (ks) __syncthreads();
    // ---- stage A (fp32 -> bf16 convert, or bf16 passthrough) ----
    if (A_F32) {
      const float* A = (const float*)Ap;
      const float* src = A + (size_t)(m0 + r) * 256 + k0 + half * 32;
      #pragma unroll
      for (int cc = 0; cc < 4; ++cc) {
        float4 f0 = *(const float4*)(src + cc * 8);
        float4 f1 = *(const float4*)(src + cc * 8 + 4);
        union { bf16x8 v; unsigned short u[8]; } pk;
        pk.u[0] = f2bf(f0.x); pk.u[1] = f2bf(f0.y);
        pk.u[2] = f2bf(f0.z); pk.u[3] = f2bf(f0.w);
        pk.u[4] = f2bf(f1.x); pk.u[5] = f2bf(f1.y);
        pk.u[6] = f2bf(f1.z); pk.u[7] = f2bf(f1.w);
        const int chunk = (half * 4 + cc) ^ (r & 7);
        *(bf16x8*)(As + r * 128 + chunk * 16) = pk.v;
      }
    } else {
      const __hip_bfloat16* A = (const __hip_bfloat16*)Ap;
      const char* src = (const char*)(A + (size_t)(m0 + r) * 256 + k0 + half * 32);
      #pragma unroll
      for (int cc = 0; cc < 4; ++cc) {
        uint4 raw = *(const uint4*)(src + cc * 16);
        const int chunk = (half * 4 + cc) ^ (r & 7);
        *(uint4*)(As + r * 128 + chunk * 16) = raw;
      }
    }
    // ---- stage B from WT rows n0+r ----
    {
      const char* src = (const char*)(BT + (size_t)(n0 + r) * 256 + k0 + half * 32);
      #pragma unroll
      for (int cc = 0; cc < 4; ++cc) {
        uint4 raw = *(const uint4*)(src + cc * 16);
        const int chunk = (half * 4 + cc) ^ (r & 7);
        *(uint4*)(Bs + r * 128 + chunk * 16) = raw;
      }
    }
    __syncthreads();
    // ---- compute: A-frag row = lane&15, k-chunk = kk*4+g ----
    bf16x8 af[4][2], bfr[4][2];
    #pragma unroll
    for (int mi = 0; mi < 4; ++mi)
      #pragma unroll
      for (int kk = 0; kk < 2; ++kk) {
        const int row = wm * 64 + mi * 16 + cx;
        const int chunk = (kk * 4 + g) ^ (row & 7);
        af[mi][kk] = *(const bf16x8*)(As + row * 128 + chunk * 16);
      }
    #pragma unroll
    for (int ni = 0; ni < 4; ++ni)
      #pragma unroll
      for (int kk = 0; kk < 2; ++kk) {
        const int row = wn * 64 + ni * 16 + cx;
        const int chunk = (kk * 4 + g) ^ (row & 7);
        bfr[ni][kk] = *(const bf16x8*)(Bs + row * 128 + chunk * 16);
      }
    #pragma unroll
    for (int kk = 0; kk < 2; ++kk)
      #pragma unroll
      for (int mi = 0; mi < 4; ++mi)
        #pragma unroll
        for (int ni = 0; ni < 4; ++ni)
          acc[mi][ni] = __builtin_amdgcn_mfma_f32_16x16x32_bf16(af[mi][kk], bfr[ni][kk], acc[mi][ni], 0, 0, 0);
  }
  // ---- epilogue: C/D layout col=lane&15, row=(lane>>4)*4+jj ----
  #pragma unroll
  for (int mi = 0; mi < 4; ++mi)
    #pragma unroll
    for (int ni = 0; ni < 4; ++ni)
      #pragma unroll
      for (int jj = 0; jj < 4; ++jj) {
        const int row = m0 + wm * 64 + mi * 16 + g * 4 + jj;
        const int col = n0 + wn * 64 + ni * 16 + cx;
        const float val = acc[mi][ni][jj];
        if (OUT_F32) ((float*)Cp)[(size_t)row * 256 + col] = val;
        else         ((__hip_bfloat16*)Cp)[(size_t)row * 256 + col] = __float2bfloat16(val);
      }
}

__global__ __launch_bounds__(256) void gemm_qkv_kernel(const float* __restrict__ Z,
                                                       const __hip_bfloat16* __restrict__ wt,
                                                       __hip_bfloat16* __restrict__ q,
                                                       __hip_bfloat16* __restrict__ k,
                                                       __hip_bfloat16* __restrict__ v) {
  const int which = blockIdx.z;
  const __hip_bfloat16* BT = wt + which * 65536;
  __hip_bfloat16* C = (which == 0) ? q : (which == 1 ? k : v);
  gemm_body<true, false>(Z, BT, C);
}

__global__ __launch_bounds__(256) void gemm_wo_kernel(const __hip_bfloat16* __restrict__ A,
                                                      const __hip_bfloat16* __restrict__ wt,
                                                      float* __restrict__ C) {
  gemm_body<false, true>(A, wt + 3 * 65536, C);
}

// ---------------- attention: one thread per (batch, head, q-row) ----------------
// q/k/v row-major bf16 [rows][256]; thread reads its 10x32 tiles (64B sectors, fully used).
__global__ __launch_bounds__(640) void attn_kernel(
    const __hip_bfloat16* __restrict__ qb, const __hip_bfloat16* __restrict__ kb,
    const __hip_bfloat16* __restrict__ vb, const int* __restrict__ roles,
    const float* __restrict__ Bp, __hip_bfloat16* __restrict__ ob, int gb0)
{
  const int t = threadIdx.x;          // 640 = 8 batches * 8 heads * 10 rows
  const int bl = t / 80;
  const int rem = t - bl * 80;
  const int h = rem / 10;
  const int i = rem - h * 10;
  const int b = blockIdx.x * 8 + bl;  // chunk-local batch
  const size_t tile = (size_t)b * 10 * 256 + h * 32;
  const size_t qoff = tile + (size_t)i * 256;

  float qf[32];
  {
    const uint4* qp = (const uint4*)(qb + qoff);
    #pragma unroll
    for (int c = 0; c < 4; ++c) {
      uint4 u = qp[c];
      qf[c*8+0] = bflo(u.x); qf[c*8+1] = bfhi(u.x);
      qf[c*8+2] = bflo(u.y); qf[c*8+3] = bfhi(u.y);
      qf[c*8+4] = bflo(u.z); qf[c*8+5] = bfhi(u.z);
      qf[c*8+6] = bflo(u.w); qf[c*8+7] = bfhi(u.w);
    }
  }
  const int ri = roles[(gb0 + b) * 10 + i];
  const float* bias_row = Bp + h * 100 + ri * 10;

  float s[10];
  #pragma unroll
  for (int j = 0; j < 10; ++j) {
    const uint4* kp = (const uint4*)(kb + tile + (size_t)j * 256);
    float a = 0.f;
    #pragma unroll
    for (int c = 0; c < 4; ++c) {
      uint4 u = kp[c];
      a += qf[c*8+0]*bflo(u.x) + qf[c*8+1]*bfhi(u.x)
         + qf[c*8+2]*bflo(u.y) + qf[c*8+3]*bfhi(u.y)
         + qf[c*8+4]*bflo(u.z) + qf[c*8+5]*bfhi(u.z)
         + qf[c*8+6]*bflo(u.w) + qf[c*8+7]*bfhi(u.w);
    }
    const int rj = roles[(gb0 + b) * 10 + j];
    s[j] = a * 0.17677669529663687f + bias_row[rj];   // 1/sqrt(32)
  }
  float mx = s[0];
  #pragma unroll
  for (int j = 1; j < 10; ++j) mx = fmaxf(mx, s[j]);
  float p[10], sum = 0.f;
  #pragma unroll
  for (int j = 0; j < 10; ++j) { p[j] = expf(s[j] - mx); sum += p[j]; }
  const float inv = 1.f / sum;

  float o[32];
  #pragma unroll
  for (int d = 0; d < 32; ++d) o[d] = 0.f;
  #pragma unroll
  for (int j = 0; j < 10; ++j) {
    const float pj = p[j] * inv;
    const uint4* vp = (const uint4*)(vb + tile + (size_t)j * 256);
    #pragma unroll
    for (int c = 0; c < 4; ++c) {
      uint4 u = vp[c];
      o[c*8+0] += pj * bflo(u.x); o[c*8+1] += pj * bfhi(u.x);
      o[c*8+2] += pj * bflo(u.y); o[c*8+3] += pj * bfhi(u.y);
      o[c*8+4] += pj * bflo(u.z); o[c*8+5] += pj * bfhi(u.z);
      o[c*8+6] += pj * bflo(u.w); o[c*8+7] += pj * bfhi(u.w);
    }
  }
  uint4* op = (uint4*)(ob + qoff);
  #pragma unroll
  for (int c = 0; c < 4; ++c) {
    uint4 u;
    u.x = (unsigned)f2bf(o[c*8+0]) | ((unsigned)f2bf(o[c*8+1]) << 16);
    u.y = (unsigned)f2bf(o[c*8+2]) | ((unsigned)f2bf(o[c*8+3]) << 16);
    u.z = (unsigned)f2bf(o[c*8+4]) | ((unsigned)f2bf(o[c*8+5]) << 16);
    u.w = (unsigned)f2bf(o[c*8+6]) | ((unsigned)f2bf(o[c*8+7]) << 16);
    op[c] = u;
  }
}

extern "C" void kernel_launch(void* const* d_in, const int* in_sizes, int n_in,
                              void* d_out, int out_size, void* d_ws, size_t ws_size,
                              hipStream_t stream)
{
  const float* Z     = (const float*)d_in[0];
  const int*   roles = (const int*)d_in[1];
  const float* WQ    = (const float*)d_in[2];
  const float* WK    = (const float*)d_in[3];
  const float* WV    = (const float*)d_in[4];
  const float* WO    = (const float*)d_in[5];
  const float* Bp    = (const float*)d_in[6];
  float* out = (float*)d_out;

  const int M = 163840;            // 16384 batches * 10 rows
  char* ws = (char*)d_ws;
  __hip_bfloat16* wt = (__hip_bfloat16*)ws;
  const size_t WT_BYTES = 4u * 256u * 256u * 2u;   // 512 KiB

  // adaptive chunking: per-row scratch = q,k,v,attn_out bf16 = 4*256*2 = 2048 B
  size_t avail = (ws_size > WT_BYTES + 256) ? (ws_size - WT_BYTES - 256) : 0;
  long maxrows = (long)(avail / 2048);
  int units = (int)(maxrows / 640);        // units of 640 rows (lcm of 128-tile and 10-row batch, /8 blocks)
  if (units < 1) units = 1;
  const int total_units = 256;             // 163840 / 640
  int nch = (total_units + units - 1) / units;
  int upc = (total_units + nch - 1) / nch;
  const int chunk_rows = upc * 640;

  __hip_bfloat16* qws = (__hip_bfloat16*)(ws + WT_BYTES);
  __hip_bfloat16* kws = qws + (size_t)chunk_rows * 256;
  __hip_bfloat16* vws = kws + (size_t)chunk_rows * 256;
  __hip_bfloat16* ows = vws + (size_t)chunk_rows * 256;

  prep_wt_kernel<<<256, 256, 0, stream>>>(WQ, WK, WV, WO, wt);

  for (int c = 0; c < nch; ++c) {
    const int r0 = c * chunk_rows;
    int rows = M - r0;
    if (rows <= 0) break;
    if (rows > chunk_rows) rows = chunk_rows;

    dim3 gq(rows / 128, 2, 3);
    gemm_qkv_kernel<<<gq, 256, 0, stream>>>(Z + (size_t)r0 * 256, wt, qws, kws, vws);

    const int batches = rows / 10;
    attn_kernel<<<batches / 8, 640, 0, stream>>>(qws, kws, vws, roles, Bp, ows, r0 / 10);

    dim3 gw(rows / 128, 2);
    gemm_wo_kernel<<<gw, 256, 0, stream>>>(ows, wt, out + (size_t)r0 * 256);
  }
}

// Round 2
// 252.538 us; speedup vs baseline: 1.6281x; 1.6281x over previous
//
#include <hip/hip_runtime.h>
#include <hip/hip_bf16.h>

// RolePositionBiasedAttention: B=16384, N=10, D=256, H=8, DH=32
// prep_wt (once) -> fused_qkv_attn (Z read once; qkv never hit HBM) -> gemm_wo

typedef __attribute__((ext_vector_type(8))) short bf16x8;
typedef __attribute__((ext_vector_type(4))) float f32x4;

__device__ __forceinline__ unsigned short f2bf(float f) {
  union { __hip_bfloat16 h; unsigned short u; } cv;
  cv.h = __float2bfloat16(f);
  return cv.u;
}
__device__ __forceinline__ float bflo(unsigned int u) { return __uint_as_float(u << 16); }
__device__ __forceinline__ float bfhi(unsigned int u) { return __uint_as_float(u & 0xffff0000u); }

// ---------------- prep: WT[w][n][k] = bf16(W[k][n]), w in {Q,K,V,O} ----------------
__global__ void prep_wt_kernel(const float* __restrict__ WQ, const float* __restrict__ WK,
                               const float* __restrict__ WV, const float* __restrict__ WO,
                               __hip_bfloat16* __restrict__ wt) {
  const int k = blockIdx.x;      // 0..255
  const int n = threadIdx.x;     // 0..255
  wt[0 * 65536 + n * 256 + k] = __float2bfloat16(WQ[k * 256 + n]);
  wt[1 * 65536 + n * 256 + k] = __float2bfloat16(WK[k * 256 + n]);
  wt[2 * 65536 + n * 256 + k] = __float2bfloat16(WV[k * 256 + n]);
  wt[3 * 65536 + n * 256 + k] = __float2bfloat16(WO[k * 256 + n]);
}

// ---------------- fused: per block = 8 batches (80 rows) ----------------
// LDS: As[80 rows][32 chunks of 16B, xor-swizzled]  (40960 B)
//      Sp strip [80][200 bf16] stride 400B: cols 0..63=q, 64..127=k, 128..191=v (32000 B)
// 4 passes over head-pairs: MFMA strip (B-frags straight from L2), barrier,
// VALU attention for 2 heads, write attn_out, barrier.
__global__ __launch_bounds__(256) void fused_qkv_attn_kernel(
    const float* __restrict__ Z, const __hip_bfloat16* __restrict__ wt,
    const int* __restrict__ roles, const float* __restrict__ Bp,
    __hip_bfloat16* __restrict__ attn_out, int gb_off)
{
  __shared__ __align__(16) char lds[72960];
  char* As = lds;
  char* Sp = lds + 40960;

  const int t = threadIdx.x;
  const int lane = t & 63;
  const int wv = t >> 6;
  const int g = lane >> 4, cx = lane & 15;
  const int blk = blockIdx.x;
  const size_t r0 = (size_t)blk * 80;       // chunk-local row base

  // ---- stage A: Z[80][256] fp32 -> bf16, xor-swizzled 16B chunks ----
  #pragma unroll
  for (int c = 0; c < 10; ++c) {
    const int idx = c * 256 + t;            // 0..2559 linear over (row, chunk)
    const int row = idx >> 5, ch = idx & 31;
    const float* src = Z + (r0 + row) * 256 + ch * 8;
    float4 f0 = *(const float4*)(src);
    float4 f1 = *(const float4*)(src + 4);
    union { bf16x8 v; unsigned short u[8]; } pk;
    pk.u[0] = f2bf(f0.x); pk.u[1] = f2bf(f0.y);
    pk.u[2] = f2bf(f0.z); pk.u[3] = f2bf(f0.w);
    pk.u[4] = f2bf(f1.x); pk.u[5] = f2bf(f1.y);
    pk.u[6] = f2bf(f1.z); pk.u[7] = f2bf(f1.w);
    *(bf16x8*)(As + row * 512 + ((ch ^ (row & 7)) * 16)) = pk.v;
  }
  __syncthreads();

  #pragma unroll 1
  for (int p = 0; p < 4; ++p) {
    // ---- GEMM: 80 x 192 strip (q|k|v for heads 2p, 2p+1) ----
    f32x4 acc[5][3];
    #pragma unroll
    for (int mi = 0; mi < 5; ++mi)
      #pragma unroll
      for (int nf = 0; nf < 3; ++nf) acc[mi][nf] = (f32x4){0.f, 0.f, 0.f, 0.f};

    const __hip_bfloat16* bptr[3];
    #pragma unroll
    for (int nf = 0; nf < 3; ++nf) {
      const int f = wv * 3 + nf;            // strip frag 0..11
      const int mf = f >> 2;                // 0=Q,1=K,2=V
      const int ncol = p * 64 + (f & 3) * 16;
      bptr[nf] = wt + mf * 65536 + (ncol + cx) * 256 + g * 8;
    }
    #pragma unroll
    for (int kk = 0; kk < 8; ++kk) {
      bf16x8 bfr[3];
      #pragma unroll
      for (int nf = 0; nf < 3; ++nf) bfr[nf] = *(const bf16x8*)(bptr[nf] + kk * 32);
      bf16x8 afr[5];
      #pragma unroll
      for (int mi = 0; mi < 5; ++mi) {
        const int row = mi * 16 + cx;
        const int ch = (kk * 4 + g) ^ (row & 7);
        afr[mi] = *(const bf16x8*)(As + row * 512 + ch * 16);
      }
      #pragma unroll
      for (int mi = 0; mi < 5; ++mi)
        #pragma unroll
        for (int nf = 0; nf < 3; ++nf)
          acc[mi][nf] = __builtin_amdgcn_mfma_f32_16x16x32_bf16(afr[mi], bfr[nf], acc[mi][nf], 0, 0, 0);
    }
    // ---- epilogue -> strip (C/D layout: col=lane&15, row=(lane>>4)*4+jj) ----
    #pragma unroll
    for (int mi = 0; mi < 5; ++mi)
      #pragma unroll
      for (int nf = 0; nf < 3; ++nf)
        #pragma unroll
        for (int jj = 0; jj < 4; ++jj) {
          const int row = mi * 16 + g * 4 + jj;
          const int col = wv * 48 + nf * 16 + cx;
          *(unsigned short*)(Sp + row * 400 + col * 2) = f2bf(acc[mi][nf][jj]);
        }
    __syncthreads();

    // ---- attention for heads 2p, 2p+1 ----
    if (t < 160) {
      const int b = t / 20;
      const int hh = (t / 10) % 2;
      const int i = t % 10;
      const int h = 2 * p + hh;
      const int gb = gb_off + blk * 8 + b;
      const char* base = Sp + (b * 10) * 400 + hh * 64;

      float qf[32];
      {
        const char* qrow = base + i * 400;   // q region offset 0
        #pragma unroll
        for (int c = 0; c < 4; ++c) {
          uint4 u = *(const uint4*)(qrow + c * 16);
          qf[c*8+0] = bflo(u.x); qf[c*8+1] = bfhi(u.x);
          qf[c*8+2] = bflo(u.y); qf[c*8+3] = bfhi(u.y);
          qf[c*8+4] = bflo(u.z); qf[c*8+5] = bfhi(u.z);
          qf[c*8+6] = bflo(u.w); qf[c*8+7] = bfhi(u.w);
        }
      }
      const int ri = roles[gb * 10 + i];
      const float* bias_row = Bp + h * 100 + ri * 10;

      float s[10];
      #pragma unroll
      for (int j = 0; j < 10; ++j) {
        const char* krow = base + j * 400 + 128;   // k region: +64 elems
        float a = 0.f;
        #pragma unroll
        for (int c = 0; c < 4; ++c) {
          uint4 u = *(const uint4*)(krow + c * 16);
          a += qf[c*8+0]*bflo(u.x) + qf[c*8+1]*bfhi(u.x)
             + qf[c*8+2]*bflo(u.y) + qf[c*8+3]*bfhi(u.y)
             + qf[c*8+4]*bflo(u.z) + qf[c*8+5]*bfhi(u.z)
             + qf[c*8+6]*bflo(u.w) + qf[c*8+7]*bfhi(u.w);
        }
        const int rj = roles[gb * 10 + j];
        s[j] = a * 0.17677669529663687f + bias_row[rj];   // 1/sqrt(32)
      }
      float mx = s[0];
      #pragma unroll
      for (int j = 1; j < 10; ++j) mx = fmaxf(mx, s[j]);
      float pr[10], sum = 0.f;
      #pragma unroll
      for (int j = 0; j < 10; ++j) { pr[j] = expf(s[j] - mx); sum += pr[j]; }
      const float inv = 1.f / sum;

      float o[32];
      #pragma unroll
      for (int d = 0; d < 32; ++d) o[d] = 0.f;
      #pragma unroll
      for (int j = 0; j < 10; ++j) {
        const float pj = pr[j] * inv;
        const char* vrow = base + j * 400 + 256;   // v region: +128 elems
        #pragma unroll
        for (int c = 0; c < 4; ++c) {
          uint4 u = *(const uint4*)(vrow + c * 16);
          o[c*8+0] += pj * bflo(u.x); o[c*8+1] += pj * bfhi(u.x);
          o[c*8+2] += pj * bflo(u.y); o[c*8+3] += pj * bfhi(u.y);
          o[c*8+4] += pj * bflo(u.z); o[c*8+5] += pj * bfhi(u.z);
          o[c*8+6] += pj * bflo(u.w); o[c*8+7] += pj * bfhi(u.w);
        }
      }
      uint4* op = (uint4*)(attn_out + (r0 + b * 10 + i) * 256 + h * 32);
      #pragma unroll
      for (int c = 0; c < 4; ++c) {
        uint4 u;
        u.x = (unsigned)f2bf(o[c*8+0]) | ((unsigned)f2bf(o[c*8+1]) << 16);
        u.y = (unsigned)f2bf(o[c*8+2]) | ((unsigned)f2bf(o[c*8+3]) << 16);
        u.z = (unsigned)f2bf(o[c*8+4]) | ((unsigned)f2bf(o[c*8+5]) << 16);
        u.w = (unsigned)f2bf(o[c*8+6]) | ((unsigned)f2bf(o[c*8+7]) << 16);
        op[c] = u;
      }
    }
    __syncthreads();
  }
}

// ---------------- WO GEMM: out[M][256] fp32 = attn_out[M][256]bf16 @ WO ----------------
// BM=64, full N=256, BK=64 x 4 steps. A-tile 8 KB LDS; B-frags from L2.
__global__ __launch_bounds__(256) void gemm_wo2_kernel(
    const __hip_bfloat16* __restrict__ A, const __hip_bfloat16* __restrict__ wt,
    float* __restrict__ C)
{
  __shared__ __align__(16) char As2[8192];
  const int t = threadIdx.x;
  const int lane = t & 63;
  const int wv = t >> 6;
  const int g = lane >> 4, cx = lane & 15;
  const size_t m0 = (size_t)blockIdx.x * 64;
  const __hip_bfloat16* WOT = wt + 3 * 65536;

  f32x4 acc[4][4];
  #pragma unroll
  for (int a = 0; a < 4; ++a)
    #pragma unroll
    for (int b = 0; b < 4; ++b) acc[a][b] = (f32x4){0.f, 0.f, 0.f, 0.f};

  #pragma unroll 1
  for (int ks = 0; ks < 4; ++ks) {
    if (ks) __syncthreads();
    #pragma unroll
    for (int c = 0; c < 2; ++c) {
      const int idx = c * 256 + t;          // 0..511 over (row, chunk)
      const int row = idx >> 3, ch = idx & 7;
      uint4 raw = *(const uint4*)(A + (m0 + row) * 256 + ks * 64 + ch * 8);
      *(uint4*)(As2 + row * 128 + ((ch ^ (row & 7)) * 16)) = raw;
    }
    __syncthreads();
    #pragma unroll
    for (int kk = 0; kk < 2; ++kk) {
      bf16x8 bfr[4];
      #pragma unroll
      for (int nf = 0; nf < 4; ++nf) {
        const int n = wv * 64 + nf * 16 + cx;
        bfr[nf] = *(const bf16x8*)(WOT + n * 256 + ks * 64 + kk * 32 + g * 8);
      }
      bf16x8 afr[4];
      #pragma unroll
      for (int mi = 0; mi < 4; ++mi) {
        const int row = mi * 16 + cx;
        const int ch = (kk * 4 + g) ^ (row & 7);
        afr[mi] = *(const bf16x8*)(As2 + row * 128 + ch * 16);
      }
      #pragma unroll
      for (int mi = 0; mi < 4; ++mi)
        #pragma unroll
        for (int nf = 0; nf < 4; ++nf)
          acc[mi][nf] = __builtin_amdgcn_mfma_f32_16x16x32_bf16(afr[mi], bfr[nf], acc[mi][nf], 0, 0, 0);
    }
  }
  #pragma unroll
  for (int mi = 0; mi < 4; ++mi)
    #pragma unroll
    for (int nf = 0; nf < 4; ++nf)
      #pragma unroll
      for (int jj = 0; jj < 4; ++jj) {
        const size_t row = m0 + mi * 16 + g * 4 + jj;
        const int col = wv * 64 + nf * 16 + cx;
        C[row * 256 + col] = acc[mi][nf][jj];
      }
}

extern "C" void kernel_launch(void* const* d_in, const int* in_sizes, int n_in,
                              void* d_out, int out_size, void* d_ws, size_t ws_size,
                              hipStream_t stream)
{
  const float* Z     = (const float*)d_in[0];
  const int*   roles = (const int*)d_in[1];
  const float* WQ    = (const float*)d_in[2];
  const float* WK    = (const float*)d_in[3];
  const float* WV    = (const float*)d_in[4];
  const float* WO    = (const float*)d_in[5];
  const float* Bp    = (const float*)d_in[6];
  float* out = (float*)d_out;

  const long M = 163840;                         // 16384 batches * 10 rows
  char* ws = (char*)d_ws;
  __hip_bfloat16* wt = (__hip_bfloat16*)ws;
  const size_t WT_BYTES = 4u * 256u * 256u * 2u; // 512 KiB
  __hip_bfloat16* attn_ws = (__hip_bfloat16*)(ws + WT_BYTES);

  // chunking (attn_out row = 512 B); chunk multiple of 320 = lcm(80, 64)
  size_t avail = (ws_size > WT_BYTES) ? (ws_size - WT_BYTES) : 0;
  long rows_fit = (long)(avail / 512);
  long chunk = (rows_fit / 320) * 320;
  if (chunk > M) chunk = M;
  if (chunk < 320) chunk = 320;                  // assume ws is at least ~164 KB

  prep_wt_kernel<<<256, 256, 0, stream>>>(WQ, WK, WV, WO, wt);

  for (long r0 = 0; r0 < M; r0 += chunk) {
    long rows = M - r0;
    if (rows > chunk) rows = chunk;
    fused_qkv_attn_kernel<<<(int)(rows / 80), 256, 0, stream>>>(
        Z + r0 * 256, wt, roles, Bp, attn_ws, (int)(r0 / 10));
    gemm_wo2_kernel<<<(int)(rows / 64), 256, 0, stream>>>(
        attn_ws, wt, out + r0 * 256);
  }
}